// Round 19
// baseline (37.413 us; speedup 1.0000x reference)
//
#include <hip/hip_runtime.h>
#include <hip/hip_bf16.h>

#define BS_   256
#define NOPS_ 2000
#define NJ_   50
#define NM_   40
#define E_    128
#define H_    128
#define NCOL_ 2001   // 1 + 50*40

typedef _Float16 f16;
using f16x8 = __attribute__((ext_vector_type(8))) _Float16;
using f16x4 = __attribute__((ext_vector_type(4))) _Float16;
using f32x4 = __attribute__((ext_vector_type(4))) float;

// ---------------------------------------------------------------------------
// R19 = R16 champion (35.3us) + micro-bundle:
//   (1) jpL/mpL row stride 134 -> 140 f16 (280B = 8B-aligned b64 reads +
//       bank-step 6 -> <=2-way = free; fixes R15's 2M conflict-cyc/rep).
//   (2) b2 in f32 regs (no per-tile cvts) [R17/R18-proven safe].
//   (3) incremental j,m in phase-2 loop (p+=128 -> j+=3,m+=8,carry) replaces
//       per-tile division.
//   (4) unroll 2 reverted (R18: neutral).
// ---------------------------------------------------------------------------
__global__ __launch_bounds__(1024, 1) void fjsp_fused(
    const float* __restrict__ ops_emb,
    const float* __restrict__ ma_emb,
    const int*   __restrict__ next_op,
    const int*   __restrict__ amask,
    const float* __restrict__ dummy,
    const float* __restrict__ W1,
    const float* __restrict__ b1,
    const float* __restrict__ W2,
    const float* __restrict__ b2,
    const float* __restrict__ W3,
    const float* __restrict__ b3,
    float* __restrict__ out)
{
  const int b    = blockIdx.x;
  const int tid  = threadIdx.x;
  const int lane = tid & 63;
  const int wave = tid >> 6;    // 0..15
  const int g    = lane >> 4;   // 0..3
  const int lr   = lane & 15;   // 0..15
  const int chalf = wave & 1;   // c-half this wave owns

  // Wlds (phase 0/1) overlaid with pvpart (phase 2) -- disjoint lifetimes.
  __shared__ __align__(16) unsigned char SMEM0[384 * 132 * 2];   // 101.4 KB
  f16 (*Wlds)[132] = reinterpret_cast<f16 (*)[132]>(SMEM0);
  float* pvpart = reinterpret_cast<float*>(SMEM0);               // [2][2016]
  __shared__ __align__(16) f16 fragL[32 * 64 * 8];               // 32 KB
  __shared__ __align__(16) f16 jpL[51][140];                     // 14.3 KB
  __shared__ __align__(16) f16 mpL[41][140];                     // 11.5 KB
  // total 159.9 KB (fits 160 KiB)

  // ========== phase 0: coalesced weight staging (all 1024 threads) ==========
  #pragma unroll
  for (int q = 0; q < 12; ++q) {
    const int idx = tid + q * 1024;
    const int row = idx >> 5, c4 = (idx & 31) * 4;
    const float* src = (row < 256) ? (W1 + (size_t)row * H_ + c4)
                                   : (W2 + (size_t)(row - 256) * H_ + c4);
    const float4 v = *reinterpret_cast<const float4*>(src);
    f16x4 h; h[0] = (f16)v.x; h[1] = (f16)v.y; h[2] = (f16)v.z; h[3] = (f16)v.w;
    *reinterpret_cast<f16x4*>(&Wlds[row][c4]) = h;
  }
  __syncthreads();

  // ========================= phase 1 (16 waves, concurrent roles) ==========
  if (wave < 8) {
    // ---- jp tile: jt = wave>>1, my c-half ----
    const int jt = wave >> 1;
    f16x8 wfr[4][4];
    #pragma unroll
    for (int f = 0; f < 4; ++f)
      #pragma unroll
      for (int cc = 0; cc < 4; ++cc) {
        const int c = chalf * 4 + cc;
        f16x8 bb;
        #pragma unroll
        for (int i = 0; i < 8; ++i) bb[i] = Wlds[32 * f + 8 * g + i][16 * c + lr];
        wfr[f][cc] = bb;
      }
    int jr = jt * 16 + lr; if (jr > 50) jr = 50;
    const float* src = (jr == 50)
        ? dummy
        : ops_emb + ((size_t)b * NOPS_ + next_op[b * NJ_ + jr]) * E_;
    const float4* ep = reinterpret_cast<const float4*>(src);
    f16x8 af[4];
    #pragma unroll
    for (int f = 0; f < 4; ++f) {
      const float4 v0 = ep[8 * f + 2 * g];
      const float4 v1 = ep[8 * f + 2 * g + 1];
      f16x8 a;
      a[0] = (f16)v0.x; a[1] = (f16)v0.y; a[2] = (f16)v0.z; a[3] = (f16)v0.w;
      a[4] = (f16)v1.x; a[5] = (f16)v1.y; a[6] = (f16)v1.z; a[7] = (f16)v1.w;
      af[f] = a;
    }
    f32x4 acc[4];
    #pragma unroll
    for (int cc = 0; cc < 4; ++cc) acc[cc] = f32x4{0.f, 0.f, 0.f, 0.f};
    #pragma unroll
    for (int f = 0; f < 4; ++f)
      #pragma unroll
      for (int cc = 0; cc < 4; ++cc)
        acc[cc] = __builtin_amdgcn_mfma_f32_16x16x32_f16(af[f], wfr[f][cc], acc[cc], 0, 0, 0);
    #pragma unroll
    for (int cc = 0; cc < 4; ++cc) {
      const int col = 16 * (chalf * 4 + cc) + lr;
      #pragma unroll
      for (int i = 0; i < 4; ++i) {
        const int row = jt * 16 + 4 * g + i;
        if (row < 51) jpL[row][col] = (f16)acc[cc][i];
      }
    }
  } else if (wave < 14) {
    // ---- mp tile: mt = (wave-8)>>1, my c-half ----
    const int mt = (wave - 8) >> 1;
    f16x8 wfr[4][4];
    #pragma unroll
    for (int f = 0; f < 4; ++f)
      #pragma unroll
      for (int cc = 0; cc < 4; ++cc) {
        const int c = chalf * 4 + cc;
        f16x8 bb;
        #pragma unroll
        for (int i = 0; i < 8; ++i)
          bb[i] = Wlds[128 + 32 * f + 8 * g + i][16 * c + lr];
        wfr[f][cc] = bb;
      }
    int mr = mt * 16 + lr; if (mr > 40) mr = 40;
    const float* src = (mr == 40) ? (dummy + E_)
                                  : ma_emb + ((size_t)b * NM_ + mr) * E_;
    const float4* ep = reinterpret_cast<const float4*>(src);
    f16x8 af[4];
    #pragma unroll
    for (int f = 0; f < 4; ++f) {
      const float4 v0 = ep[8 * f + 2 * g];
      const float4 v1 = ep[8 * f + 2 * g + 1];
      f16x8 a;
      a[0] = (f16)v0.x; a[1] = (f16)v0.y; a[2] = (f16)v0.z; a[3] = (f16)v0.w;
      a[4] = (f16)v1.x; a[5] = (f16)v1.y; a[6] = (f16)v1.z; a[7] = (f16)v1.w;
      af[f] = a;
    }
    f32x4 acc[4];
    #pragma unroll
    for (int cc = 0; cc < 4; ++cc) {
      const float binit = b1[16 * (chalf * 4 + cc) + lr];
      acc[cc] = f32x4{binit, binit, binit, binit};
    }
    #pragma unroll
    for (int f = 0; f < 4; ++f)
      #pragma unroll
      for (int cc = 0; cc < 4; ++cc)
        acc[cc] = __builtin_amdgcn_mfma_f32_16x16x32_f16(af[f], wfr[f][cc], acc[cc], 0, 0, 0);
    #pragma unroll
    for (int cc = 0; cc < 4; ++cc) {
      const int col = 16 * (chalf * 4 + cc) + lr;
      #pragma unroll
      for (int i = 0; i < 4; ++i) {
        const int row = mt * 16 + 4 * g + i;
        if (row < 41) mpL[row][col] = (f16)acc[cc][i];
      }
    }
  } else {
    // ---- fragL builder (16 frags each) + mask passthrough ----
    #pragma unroll 4
    for (int q = 0; q < 16; ++q) {
      const int t = (wave - 14) * 16 + q;
      const int f = t >> 3, c = t & 7;
      f16x8 bb;
      #pragma unroll
      for (int i = 0; i < 8; ++i)
        bb[i] = Wlds[256 + 32 * f + 8 * g + i][16 * c + lr];
      *reinterpret_cast<f16x8*>(&fragL[((size_t)t * 64 + lane) * 8]) = bb;
    }
    const int base  = (wave == 14) ? 0 : 1001;
    const int count = (wave == 14) ? 1001 : 1000;
    const int* mrow = amask + (size_t)b * NCOL_ + base;
    float* __restrict__ orow = out + (size_t)BS_ * NCOL_ + (size_t)b * NCOL_ + base;
    for (int i = lane; i < count; i += 64) orow[i] = mrow[i] != 0 ? 1.0f : 0.0f;
  }
  __syncthreads();

  // ========================= phase 2: 8 groups x 2 c-halves ================
  {
    const int gp = wave >> 1;            // tile group 0..7
    f16x8 w2f[4][4];
    #pragma unroll
    for (int f = 0; f < 4; ++f)
      #pragma unroll
      for (int cc = 0; cc < 4; ++cc)
        w2f[f][cc] = *reinterpret_cast<const f16x8*>(
            &fragL[((size_t)(f * 8 + chalf * 4 + cc) * 64 + lane) * 8]);
    float4 b2v[4], w3v[4];               // f32: no per-tile cvts
    #pragma unroll
    for (int cc = 0; cc < 4; ++cc) {
      const int c = chalf * 4 + cc;
      b2v[cc] = *reinterpret_cast<const float4*>(b2 + 16 * c + 4 * g);
      w3v[cc] = *reinterpret_cast<const float4*>(W3 + 16 * c + 4 * g);
    }
    float* pvp = pvpart + chalf * 2016;

    // incremental j,m: p starts at gp*16+lr, steps by 128 = 3*40 + 8
    int p = gp * 16 + lr;
    int j = p / 40;
    int m = p - j * 40;

    #pragma unroll 1
    for (int t = gp; t < 126; t += 8) {
      // noop special-case: p>=2000 reads (j,m)=(50,40); else running (j,m)
      const int jj = (p < 2000) ? j : 50;
      const int mm = (p < 2000) ? m : 40;
      f32x4 acc[4];
      #pragma unroll
      for (int cc = 0; cc < 4; ++cc)
        acc[cc] = f32x4{b2v[cc].x, b2v[cc].y, b2v[cc].z, b2v[cc].w};
      #pragma unroll
      for (int f = 0; f < 4; ++f) {
        const f16x4 jlo = *reinterpret_cast<const f16x4*>(&jpL[jj][32 * f + 8 * g]);
        const f16x4 jhi = *reinterpret_cast<const f16x4*>(&jpL[jj][32 * f + 8 * g + 4]);
        const f16x4 mlo = *reinterpret_cast<const f16x4*>(&mpL[mm][32 * f + 8 * g]);
        const f16x4 mhi = *reinterpret_cast<const f16x4*>(&mpL[mm][32 * f + 8 * g + 4]);
        const f16x4 z   = {(f16)0.f, (f16)0.f, (f16)0.f, (f16)0.f};
        const f16x4 slo = __builtin_elementwise_max(jlo + mlo, z);
        const f16x4 shi = __builtin_elementwise_max(jhi + mhi, z);
        const f16x8 afr = __builtin_shufflevector(slo, shi, 0, 1, 2, 3, 4, 5, 6, 7);
        #pragma unroll
        for (int cc = 0; cc < 4; ++cc)   // SWAPPED: A = W2^T frag, B = h1^T
          acc[cc] = __builtin_amdgcn_mfma_f32_16x16x32_f16(w2f[f][cc], afr, acc[cc], 0, 0, 0);
      }
      float pv = 0.f;
      #pragma unroll
      for (int cc = 0; cc < 4; ++cc) {
        pv = fmaf(fmaxf(acc[cc][0], 0.f), w3v[cc].x, pv);
        pv = fmaf(fmaxf(acc[cc][1], 0.f), w3v[cc].y, pv);
        pv = fmaf(fmaxf(acc[cc][2], 0.f), w3v[cc].z, pv);
        pv = fmaf(fmaxf(acc[cc][3], 0.f), w3v[cc].w, pv);
      }
      pv += __shfl_xor(pv, 16);
      pv += __shfl_xor(pv, 32);
      if (g == 0) pvp[p] = pv;            // partial for my c-half
      // advance: p += 128 -> j += 3, m += 8 (carry)
      p += 128; j += 3; m += 8;
      if (m >= 40) { m -= 40; ++j; }
    }
  }
  __syncthreads();

  // ==================== combine: pv = halfA + halfB + b3 ===================
  {
    const float bias3 = b3[0];
    float* __restrict__ outb = out + (size_t)b * NCOL_;
    #pragma unroll
    for (int q = 0; q < 2; ++q) {
      const int p = tid + q * 1024;
      if (p <= 2000) {
        const float v = pvpart[p] + pvpart[2016 + p] + bias3;
        outb[(p == 2000) ? 0 : (p + 1)] = v;
      }
    }
  }
}

extern "C" void kernel_launch(void* const* d_in, const int* in_sizes, int n_in,
                              void* d_out, int out_size, void* d_ws, size_t ws_size,
                              hipStream_t stream) {
  (void)in_sizes; (void)n_in; (void)d_ws; (void)ws_size; (void)out_size;
  fjsp_fused<<<dim3(BS_), dim3(1024), 0, stream>>>(
      (const float*)d_in[0],   // ops_emb
      (const float*)d_in[1],   // ma_emb
      (const int*)d_in[2],     // next_op
      (const int*)d_in[3],     // action_mask (bool -> int32)
      (const float*)d_in[4],   // dummy
      (const float*)d_in[5],   // W1
      (const float*)d_in[6],   // b1
      (const float*)d_in[7],   // W2
      (const float*)d_in[8],   // b2
      (const float*)d_in[9],   // W3
      (const float*)d_in[10],  // b3
      (float*)d_out);
}

// Round 20
// 35.065 us; speedup vs baseline: 1.0670x; 1.0670x over previous
//
#include <hip/hip_runtime.h>
#include <hip/hip_bf16.h>

#define BS_   256
#define NOPS_ 2000
#define NJ_   50
#define NM_   40
#define E_    128
#define H_    128
#define NCOL_ 2001   // 1 + 50*40

typedef _Float16 f16;
using f16x8 = __attribute__((ext_vector_type(8))) _Float16;
using f16x4 = __attribute__((ext_vector_type(4))) _Float16;
using f32x4 = __attribute__((ext_vector_type(4))) float;

// ---------------------------------------------------------------------------
// FINAL (champion lock): R16 verbatim — measured 35.3us, the best of 20 rounds.
// Structure: one 1024-thread block (16 waves, 4 waves/SIMD) per batch element.
// dummy folded in as jp-row 50 / mp-row 40; noop logit = pair index 2000.
// Phase 0: coalesced W1+W2 f32->f16 staging into LDS.
// Phase 1: waves 0-7 jp-tiles (c-half split), 8-13 mp-tiles, 14-15 fragL+mask.
// Phase 2: swapped MFMA (D = W2^T.h1^T), c-half partials to LDS, combine.
// Spill-free at the 128-VGPR cap (R15-verified); occupancy at the VGPR ceiling.
// ---------------------------------------------------------------------------
__global__ __launch_bounds__(1024, 1) void fjsp_fused(
    const float* __restrict__ ops_emb,
    const float* __restrict__ ma_emb,
    const int*   __restrict__ next_op,
    const int*   __restrict__ amask,
    const float* __restrict__ dummy,
    const float* __restrict__ W1,
    const float* __restrict__ b1,
    const float* __restrict__ W2,
    const float* __restrict__ b2,
    const float* __restrict__ W3,
    const float* __restrict__ b3,
    float* __restrict__ out)
{
  const int b    = blockIdx.x;
  const int tid  = threadIdx.x;
  const int lane = tid & 63;
  const int wave = tid >> 6;    // 0..15
  const int g    = lane >> 4;   // 0..3
  const int lr   = lane & 15;   // 0..15
  const int chalf = wave & 1;   // c-half this wave owns

  // Wlds (phase 0/1) overlaid with pvpart (phase 2) -- disjoint lifetimes.
  __shared__ __align__(16) unsigned char SMEM0[384 * 132 * 2];   // 101.4 KB
  f16 (*Wlds)[132] = reinterpret_cast<f16 (*)[132]>(SMEM0);
  float* pvpart = reinterpret_cast<float*>(SMEM0);               // [2][2016]
  __shared__ __align__(16) f16 fragL[32 * 64 * 8];               // 32 KB
  __shared__ __align__(16) f16 jpL[51][134];                     // 13.7 KB
  __shared__ __align__(16) f16 mpL[41][134];                     // 11.0 KB

  // ========== phase 0: coalesced weight staging (all 1024 threads) ==========
  #pragma unroll
  for (int q = 0; q < 12; ++q) {
    const int idx = tid + q * 1024;
    const int row = idx >> 5, c4 = (idx & 31) * 4;
    const float* src = (row < 256) ? (W1 + (size_t)row * H_ + c4)
                                   : (W2 + (size_t)(row - 256) * H_ + c4);
    const float4 v = *reinterpret_cast<const float4*>(src);
    f16x4 h; h[0] = (f16)v.x; h[1] = (f16)v.y; h[2] = (f16)v.z; h[3] = (f16)v.w;
    *reinterpret_cast<f16x4*>(&Wlds[row][c4]) = h;
  }
  __syncthreads();

  // ========================= phase 1 (16 waves, concurrent roles) ==========
  if (wave < 8) {
    // ---- jp tile: jt = wave>>1, my c-half ----
    const int jt = wave >> 1;
    f16x8 wfr[4][4];
    #pragma unroll
    for (int f = 0; f < 4; ++f)
      #pragma unroll
      for (int cc = 0; cc < 4; ++cc) {
        const int c = chalf * 4 + cc;
        f16x8 bb;
        #pragma unroll
        for (int i = 0; i < 8; ++i) bb[i] = Wlds[32 * f + 8 * g + i][16 * c + lr];
        wfr[f][cc] = bb;
      }
    int jr = jt * 16 + lr; if (jr > 50) jr = 50;
    const float* src = (jr == 50)
        ? dummy
        : ops_emb + ((size_t)b * NOPS_ + next_op[b * NJ_ + jr]) * E_;
    const float4* ep = reinterpret_cast<const float4*>(src);
    f16x8 af[4];
    #pragma unroll
    for (int f = 0; f < 4; ++f) {
      const float4 v0 = ep[8 * f + 2 * g];
      const float4 v1 = ep[8 * f + 2 * g + 1];
      f16x8 a;
      a[0] = (f16)v0.x; a[1] = (f16)v0.y; a[2] = (f16)v0.z; a[3] = (f16)v0.w;
      a[4] = (f16)v1.x; a[5] = (f16)v1.y; a[6] = (f16)v1.z; a[7] = (f16)v1.w;
      af[f] = a;
    }
    f32x4 acc[4];
    #pragma unroll
    for (int cc = 0; cc < 4; ++cc) acc[cc] = f32x4{0.f, 0.f, 0.f, 0.f};
    #pragma unroll
    for (int f = 0; f < 4; ++f)
      #pragma unroll
      for (int cc = 0; cc < 4; ++cc)
        acc[cc] = __builtin_amdgcn_mfma_f32_16x16x32_f16(af[f], wfr[f][cc], acc[cc], 0, 0, 0);
    #pragma unroll
    for (int cc = 0; cc < 4; ++cc) {
      const int col = 16 * (chalf * 4 + cc) + lr;
      #pragma unroll
      for (int i = 0; i < 4; ++i) {
        const int row = jt * 16 + 4 * g + i;
        if (row < 51) jpL[row][col] = (f16)acc[cc][i];
      }
    }
  } else if (wave < 14) {
    // ---- mp tile: mt = (wave-8)>>1, my c-half ----
    const int mt = (wave - 8) >> 1;
    f16x8 wfr[4][4];
    #pragma unroll
    for (int f = 0; f < 4; ++f)
      #pragma unroll
      for (int cc = 0; cc < 4; ++cc) {
        const int c = chalf * 4 + cc;
        f16x8 bb;
        #pragma unroll
        for (int i = 0; i < 8; ++i)
          bb[i] = Wlds[128 + 32 * f + 8 * g + i][16 * c + lr];
        wfr[f][cc] = bb;
      }
    int mr = mt * 16 + lr; if (mr > 40) mr = 40;
    const float* src = (mr == 40) ? (dummy + E_)
                                  : ma_emb + ((size_t)b * NM_ + mr) * E_;
    const float4* ep = reinterpret_cast<const float4*>(src);
    f16x8 af[4];
    #pragma unroll
    for (int f = 0; f < 4; ++f) {
      const float4 v0 = ep[8 * f + 2 * g];
      const float4 v1 = ep[8 * f + 2 * g + 1];
      f16x8 a;
      a[0] = (f16)v0.x; a[1] = (f16)v0.y; a[2] = (f16)v0.z; a[3] = (f16)v0.w;
      a[4] = (f16)v1.x; a[5] = (f16)v1.y; a[6] = (f16)v1.z; a[7] = (f16)v1.w;
      af[f] = a;
    }
    f32x4 acc[4];
    #pragma unroll
    for (int cc = 0; cc < 4; ++cc) {
      const float binit = b1[16 * (chalf * 4 + cc) + lr];
      acc[cc] = f32x4{binit, binit, binit, binit};
    }
    #pragma unroll
    for (int f = 0; f < 4; ++f)
      #pragma unroll
      for (int cc = 0; cc < 4; ++cc)
        acc[cc] = __builtin_amdgcn_mfma_f32_16x16x32_f16(af[f], wfr[f][cc], acc[cc], 0, 0, 0);
    #pragma unroll
    for (int cc = 0; cc < 4; ++cc) {
      const int col = 16 * (chalf * 4 + cc) + lr;
      #pragma unroll
      for (int i = 0; i < 4; ++i) {
        const int row = mt * 16 + 4 * g + i;
        if (row < 41) mpL[row][col] = (f16)acc[cc][i];
      }
    }
  } else {
    // ---- fragL builder (16 frags each) + mask passthrough ----
    #pragma unroll 4
    for (int q = 0; q < 16; ++q) {
      const int t = (wave - 14) * 16 + q;
      const int f = t >> 3, c = t & 7;
      f16x8 bb;
      #pragma unroll
      for (int i = 0; i < 8; ++i)
        bb[i] = Wlds[256 + 32 * f + 8 * g + i][16 * c + lr];
      *reinterpret_cast<f16x8*>(&fragL[((size_t)t * 64 + lane) * 8]) = bb;
    }
    const int base  = (wave == 14) ? 0 : 1001;
    const int count = (wave == 14) ? 1001 : 1000;
    const int* mrow = amask + (size_t)b * NCOL_ + base;
    float* __restrict__ orow = out + (size_t)BS_ * NCOL_ + (size_t)b * NCOL_ + base;
    for (int i = lane; i < count; i += 64) orow[i] = mrow[i] != 0 ? 1.0f : 0.0f;
  }
  __syncthreads();

  // ========================= phase 2: 8 groups x 2 c-halves ================
  {
    const int gp = wave >> 1;            // tile group 0..7
    f16x8 w2f[4][4];
    #pragma unroll
    for (int f = 0; f < 4; ++f)
      #pragma unroll
      for (int cc = 0; cc < 4; ++cc)
        w2f[f][cc] = *reinterpret_cast<const f16x8*>(
            &fragL[((size_t)(f * 8 + chalf * 4 + cc) * 64 + lane) * 8]);
    f16x4 b2h[4];
    float4 w3v[4];
    #pragma unroll
    for (int cc = 0; cc < 4; ++cc) {
      const int c = chalf * 4 + cc;
      const float4 bv = *reinterpret_cast<const float4*>(b2 + 16 * c + 4 * g);
      f16x4 hh; hh[0] = (f16)bv.x; hh[1] = (f16)bv.y; hh[2] = (f16)bv.z; hh[3] = (f16)bv.w;
      b2h[cc] = hh;
      w3v[cc] = *reinterpret_cast<const float4*>(W3 + 16 * c + 4 * g);
    }
    float* pvp = pvpart + chalf * 2016;

    #pragma unroll 1
    for (int t = gp; t < 126; t += 8) {
      const int p  = t * 16 + lr;         // pair index, 2000 = noop
      const int p2 = (p < 2000) ? p : 2000;
      int j, m;
      if (p2 == 2000) { j = 50; m = 40; }
      else            { j = p2 / 40; m = p2 - j * 40; }
      f32x4 acc[4];
      #pragma unroll
      for (int cc = 0; cc < 4; ++cc)
        acc[cc] = f32x4{(float)b2h[cc][0], (float)b2h[cc][1],
                        (float)b2h[cc][2], (float)b2h[cc][3]};
      #pragma unroll
      for (int f = 0; f < 4; ++f) {
        const f16x4 jlo = *reinterpret_cast<const f16x4*>(&jpL[j][32 * f + 8 * g]);
        const f16x4 jhi = *reinterpret_cast<const f16x4*>(&jpL[j][32 * f + 8 * g + 4]);
        const f16x4 mlo = *reinterpret_cast<const f16x4*>(&mpL[m][32 * f + 8 * g]);
        const f16x4 mhi = *reinterpret_cast<const f16x4*>(&mpL[m][32 * f + 8 * g + 4]);
        const f16x4 z   = {(f16)0.f, (f16)0.f, (f16)0.f, (f16)0.f};
        const f16x4 slo = __builtin_elementwise_max(jlo + mlo, z);
        const f16x4 shi = __builtin_elementwise_max(jhi + mhi, z);
        const f16x8 afr = __builtin_shufflevector(slo, shi, 0, 1, 2, 3, 4, 5, 6, 7);
        #pragma unroll
        for (int cc = 0; cc < 4; ++cc)   // SWAPPED: A = W2^T frag, B = h1^T
          acc[cc] = __builtin_amdgcn_mfma_f32_16x16x32_f16(w2f[f][cc], afr, acc[cc], 0, 0, 0);
      }
      float pv = 0.f;
      #pragma unroll
      for (int cc = 0; cc < 4; ++cc) {
        pv = fmaf(fmaxf(acc[cc][0], 0.f), w3v[cc].x, pv);
        pv = fmaf(fmaxf(acc[cc][1], 0.f), w3v[cc].y, pv);
        pv = fmaf(fmaxf(acc[cc][2], 0.f), w3v[cc].z, pv);
        pv = fmaf(fmaxf(acc[cc][3], 0.f), w3v[cc].w, pv);
      }
      pv += __shfl_xor(pv, 16);
      pv += __shfl_xor(pv, 32);
      if (g == 0) pvp[p] = pv;            // partial for my c-half
    }
  }
  __syncthreads();

  // ==================== combine: pv = halfA + halfB + b3 ===================
  {
    const float bias3 = b3[0];
    float* __restrict__ outb = out + (size_t)b * NCOL_;
    #pragma unroll
    for (int q = 0; q < 2; ++q) {
      const int p = tid + q * 1024;
      if (p <= 2000) {
        const float v = pvpart[p] + pvpart[2016 + p] + bias3;
        outb[(p == 2000) ? 0 : (p + 1)] = v;
      }
    }
  }
}

extern "C" void kernel_launch(void* const* d_in, const int* in_sizes, int n_in,
                              void* d_out, int out_size, void* d_ws, size_t ws_size,
                              hipStream_t stream) {
  (void)in_sizes; (void)n_in; (void)d_ws; (void)ws_size; (void)out_size;
  fjsp_fused<<<dim3(BS_), dim3(1024), 0, stream>>>(
      (const float*)d_in[0],   // ops_emb
      (const float*)d_in[1],   // ma_emb
      (const int*)d_in[2],     // next_op
      (const int*)d_in[3],     // action_mask (bool -> int32)
      (const float*)d_in[4],   // dummy
      (const float*)d_in[5],   // W1
      (const float*)d_in[6],   // b1
      (const float*)d_in[7],   // W2
      (const float*)d_in[8],   // b2
      (const float*)d_in[9],   // W3
      (const float*)d_in[10],  // b3
      (float*)d_out);
}